// Round 2
// baseline (860.081 us; speedup 1.0000x reference)
//
#include <hip/hip_runtime.h>
#include <hip/hip_bf16.h>
#include <stdint.h>

#define B_N   16
#define C_IN  512
#define H_    64
#define W_    64
#define C_OUT 512
#define LAT   512

// runtime_coef = sqrt(2/(9*512)) = 1/48 exactly
#define RC      (1.0f/48.0f)
#define FC_COEF 0.044194173824159216f  // 1/sqrt(512)

typedef __attribute__((ext_vector_type(8))) short short8;
typedef __attribute__((ext_vector_type(4))) float f32x4;

typedef const void __attribute__((address_space(1))) gvoid_t;
typedef void __attribute__((address_space(3))) lvoid_t;

__device__ __forceinline__ unsigned short f2bf(float f) {
  union { float f; unsigned u; } v; v.f = f;
  unsigned r = v.u + 0x7FFFu + ((v.u >> 16) & 1u);
  return (unsigned short)(r >> 16);
}

__device__ __forceinline__ void gload_lds16(const unsigned short* g, unsigned short* l) {
  __builtin_amdgcn_global_load_lds((gvoid_t*)g, (lvoid_t*)l, 16, 0, 0);
}

// ---------------- kernel 1: style s[b][c] = fc_coef * (y @ fc_w) + bias + 1
__global__ void style_k(const float* __restrict__ y, const float* __restrict__ fcw,
                        const float* __restrict__ bias, float* __restrict__ s) {
  int b = blockIdx.x;
  int c = threadIdx.x;            // 512 threads
  __shared__ float ys[LAT];
  ys[c] = y[b * LAT + c];
  __syncthreads();
  float acc = 0.f;
  for (int l = 0; l < LAT; ++l) acc += ys[l] * fcw[l * C_IN + c];
  s[b * C_IN + c] = acc * FC_COEF + bias[c] + 1.0f;
}

// ---------------- kernel 2: wb[tap][o][c] = bf16(w*RC)  (transposed), t[c][o] = sum_tap (w*RC)^2
__global__ void wtrans_k(const float* __restrict__ w, unsigned short* __restrict__ wb,
                         float* __restrict__ t) {
  // grid (C_OUT/64, C_IN/64), block 256
  const int o0 = blockIdx.x * 64, c0 = blockIdx.y * 64;
  __shared__ unsigned short tile[64][66];
  const int tid = threadIdx.x;
  float acc[16];
#pragma unroll
  for (int i = 0; i < 16; ++i) acc[i] = 0.f;
  for (int tap = 0; tap < 9; ++tap) {
    __syncthreads();  // protect tile from previous iteration's reads
#pragma unroll
    for (int i = 0; i < 16; ++i) {
      int row = i * 4 + (tid >> 6);   // c offset
      int col = tid & 63;             // o offset
      float v = w[(tap * C_IN + c0 + row) * C_OUT + o0 + col] * RC;
      acc[i] += v * v;
      tile[row][col] = f2bf(v);
    }
    __syncthreads();
#pragma unroll
    for (int i = 0; i < 16; ++i) {
      int row = i * 4 + (tid >> 6);   // o offset
      int col = tid & 63;             // c offset
      wb[(tap * C_OUT + o0 + row) * C_IN + c0 + col] = tile[col][row];
    }
  }
#pragma unroll
  for (int i = 0; i < 16; ++i) {
    int row = i * 4 + (tid >> 6), col = tid & 63;
    t[(c0 + row) * C_OUT + o0 + col] = acc[i];
  }
}

// ---------------- kernel 3: d[b][o] = rsqrt(sum_c s^2 * t + eps)
__global__ void demod_k(const float* __restrict__ s, const float* __restrict__ t,
                        float* __restrict__ d) {
  int b = blockIdx.x;
  int o = threadIdx.x;            // 512 threads
  __shared__ float ss[C_IN];
  ss[o] = s[b * C_IN + o];
  __syncthreads();
  float acc = 0.f;
  for (int c = 0; c < C_IN; ++c) acc += ss[c] * ss[c] * t[c * C_OUT + o];
  d[b * C_OUT + o] = rsqrtf(acc + 1e-8f);
}

// ---------------- kernel 4: xb[b][h][w][c] = bf16(x[b][c][h][w] * s[b][c])  (NCHW -> NHWC)
__global__ void modx_k(const float* __restrict__ x, const float* __restrict__ s,
                       unsigned short* __restrict__ xb) {
  // grid (H_, C_IN/64, B_N), block 256
  const int h = blockIdx.x, c0 = blockIdx.y * 64, b = blockIdx.z;
  __shared__ unsigned short tile[64][66];
  const int tid = threadIdx.x;
#pragma unroll
  for (int i = 0; i < 16; ++i) {
    int row = i * 4 + (tid >> 6);   // c offset
    int col = tid & 63;             // w
    float v = x[((b * C_IN + c0 + row) * H_ + h) * W_ + col] * s[b * C_IN + c0 + row];
    tile[row][col] = f2bf(v);
  }
  __syncthreads();
#pragma unroll
  for (int i = 0; i < 16; ++i) {
    int row = i * 4 + (tid >> 6);   // w
    int col = tid & 63;             // c offset
    xb[((b * H_ + h) * W_ + row) * C_IN + c0 + col] = tile[col][row];
  }
}

// ---------------- kernel 5: the conv (implicit GEMM, bf16 MFMA 16x16x32)
// grid (32 pixel-blocks, 4 cout-blocks, 16 batch), block 256 (4 waves, each 64x64)
__global__ __launch_bounds__(256, 3)
void conv_k(const unsigned short* __restrict__ xb,
            const unsigned short* __restrict__ wb,
            const float* __restrict__ d,
            float* __restrict__ out) {
  __shared__ __align__(16) unsigned short lds[24576];  // xs 2*8192 + wt 2*4096 shorts = 48 KB
  unsigned short* xs0 = lds;
  unsigned short* wt0 = lds + 16384;

  const int tid = threadIdx.x;
  const int pb = blockIdx.x;
  const int ob = blockIdx.y;
  const int b  = blockIdx.z;
  const int p0 = pb * 128;
  const int h0 = pb * 2;
  const int o0 = ob * 128;

  const int lane = tid & 63;
  const int wv   = tid >> 6;
  const int wm   = wv >> 1;
  const int wn   = wv & 1;
  const int kg   = lane >> 4;    // k-octet 0..3
  const int l16  = lane & 15;

  // A-frag LDS short-offsets are loop-invariant
  int a_off[4];
#pragma unroll
  for (int mf = 0; mf < 4; ++mf) {
    int m = wm * 64 + mf * 16 + l16;
    a_off[mf] = (m * 4 + (kg ^ ((m >> 1) & 3))) * 8;
  }
  int prr[4], pcc[4];
#pragma unroll
  for (int nf = 0; nf < 4; ++nf) {
    int p = wn * 64 + nf * 16 + l16;
    prr[nf] = p >> 6;
    pcc[nf] = p & 63;
  }

  const f32x4 fzero = {0.f, 0.f, 0.f, 0.f};
  const short8 szero = {0, 0, 0, 0, 0, 0, 0, 0};
  f32x4 acc[4][4];
#pragma unroll
  for (int i = 0; i < 4; ++i)
#pragma unroll
    for (int j = 0; j < 4; ++j) acc[i][j] = fzero;

  const unsigned short* xbb = xb + b * (H_ * W_ * C_IN);

  // stage x tile: 4 halo rows x 64 cols x 32 ch, 16B slots, XOR-swizzled source
  auto stage_x = [&](unsigned short* dst, int c0) {
#pragma unroll
    for (int i = 0; i < 4; ++i) {
      int col = tid >> 2, s = tid & 3;
      int g = s ^ ((col >> 1) & 3);
      int h = h0 - 1 + i;
      unsigned short* ldst = dst + (i * 256 + tid) * 8;
      if ((unsigned)h < 64u) {
        gload_lds16(xbb + ((h * 64 + col) * 512 + c0 + g * 8), ldst);
      } else {
        *(f32x4*)ldst = fzero;   // zero-pad rows outside the image
      }
    }
  };
  // stage weight tile: 128 couts x 32 ch
  auto stage_w = [&](unsigned short* dst, int tap, int c0) {
#pragma unroll
    for (int i = 0; i < 2; ++i) {
      int m = i * 64 + (tid >> 2), s = tid & 3;
      int g = s ^ ((m >> 1) & 3);
      gload_lds16(wb + (tap * C_OUT + o0 + m) * C_IN + c0 + g * 8,
                  dst + (i * 256 + tid) * 8);
    }
  };

  stage_x(xs0, 0);
  stage_w(wt0, 0, 0);
  __syncthreads();

  for (int chunk = 0; chunk < 16; ++chunk) {
    const int c0 = chunk * 32;
    unsigned short* xs = xs0 + (chunk & 1) * 8192;
#pragma unroll
    for (int tap = 0; tap < 9; ++tap) {
      unsigned short* wt  = wt0 + ((chunk + tap) & 1) * 4096;
      unsigned short* wtn = wt0 + (((chunk + tap) & 1) ^ 1) * 4096;
      if (tap < 8) {
        stage_w(wtn, tap + 1, c0);
      } else if (chunk + 1 < 16) {
        stage_x(xs0 + ((chunk & 1) ^ 1) * 8192, c0 + 32);
        stage_w(wtn, 0, c0 + 32);
      }
      const int kh = tap / 3;
      const int kw = tap % 3;

      short8 af[4];
#pragma unroll
      for (int mf = 0; mf < 4; ++mf)
        af[mf] = *(const short8*)(wt + a_off[mf]);

      short8 bfr[4];
#pragma unroll
      for (int nf = 0; nf < 4; ++nf) {
        int r  = prr[nf] + kh;                 // 0..3 within halo tile
        int ct = pcc[nf] + kw - 1;             // shifted column
        bool vd = (unsigned)ct < 64u;
        int ctc = ct & 63;
        int slot = (r * 64 + ctc) * 4 + (kg ^ ((ctc >> 1) & 3));
        short8 tv = *(const short8*)(xs + slot * 8);
        bfr[nf] = vd ? tv : szero;             // zero-pad columns outside the image
      }
#pragma unroll
      for (int mf = 0; mf < 4; ++mf)
#pragma unroll
        for (int nf = 0; nf < 4; ++nf)
          acc[mf][nf] = __builtin_amdgcn_mfma_f32_16x16x32_bf16(af[mf], bfr[nf], acc[mf][nf], 0, 0, 0);
      __syncthreads();
    }
  }

  // epilogue: out[b][o][p] = acc * d[b][o]
  const float* db = d + b * C_OUT;
  float* obase = out + (size_t)b * C_OUT * 4096;
#pragma unroll
  for (int mf = 0; mf < 4; ++mf) {
#pragma unroll
    for (int rg = 0; rg < 4; ++rg) {
      int o = o0 + wm * 64 + mf * 16 + kg * 4 + rg;
      float dv = db[o];
      float* orow = obase + (size_t)o * 4096 + p0 + wn * 64;
#pragma unroll
      for (int nf = 0; nf < 4; ++nf)
        orow[nf * 16 + l16] = acc[mf][nf][rg] * dv;
    }
  }
}

extern "C" void kernel_launch(void* const* d_in, const int* in_sizes, int n_in,
                              void* d_out, int out_size, void* d_ws, size_t ws_size,
                              hipStream_t stream) {
  const float* x    = (const float*)d_in[0];
  const float* y    = (const float*)d_in[1];
  const float* w    = (const float*)d_in[2];
  const float* fcw  = (const float*)d_in[3];
  const float* bias = (const float*)d_in[4];
  float* out = (float*)d_out;

  char* ws = (char*)d_ws;
  float* s_buf          = (float*)(ws);                    //  32 KB  s[16][512]
  float* d_buf          = (float*)(ws + 32768);            //  32 KB  d[16][512]
  float* t_buf          = (float*)(ws + 65536);            //   1 MB  t[512][512]
  unsigned short* wbuf  = (unsigned short*)(ws + 1114112); // 4.5 MB  wb[9][512][512] bf16
  unsigned short* xbuf  = (unsigned short*)(ws + 5832704); //  64 MB  xb[16][64][64][512] bf16

  style_k<<<dim3(16), dim3(512), 0, stream>>>(y, fcw, bias, s_buf);
  wtrans_k<<<dim3(8, 8), dim3(256), 0, stream>>>(w, wbuf, t_buf);
  demod_k<<<dim3(16), dim3(512), 0, stream>>>(s_buf, t_buf, d_buf);
  modx_k<<<dim3(64, 8, 16), dim3(256), 0, stream>>>(x, s_buf, xbuf);
  conv_k<<<dim3(32, 4, 16), dim3(256), 0, stream>>>(xbuf, wbuf, d_buf, out);
}

// Round 5
// 762.640 us; speedup vs baseline: 1.1278x; 1.1278x over previous
//
#include <hip/hip_runtime.h>
#include <hip/hip_bf16.h>
#include <stdint.h>

#define B_N   16
#define C_IN  512
#define H_    64
#define W_    64
#define C_OUT 512
#define LAT   512

// runtime_coef = sqrt(2/(9*512)) = 1/48 exactly
#define RC      (1.0f/48.0f)
#define FC_COEF 0.044194173824159216f  // 1/sqrt(512)

typedef __attribute__((ext_vector_type(8))) short short8;
typedef __attribute__((ext_vector_type(4))) float f32x4;

typedef const void __attribute__((address_space(1))) gvoid_t;
typedef void __attribute__((address_space(3))) lvoid_t;

__device__ __forceinline__ unsigned short f2bf(float f) {
  union { float f; unsigned u; } v; v.f = f;
  unsigned r = v.u + 0x7FFFu + ((v.u >> 16) & 1u);
  return (unsigned short)(r >> 16);
}

__device__ __forceinline__ void gload_lds16(const unsigned short* g, unsigned short* l) {
  __builtin_amdgcn_global_load_lds((gvoid_t*)g, (lvoid_t*)l, 16, 0, 0);
}

// ---------------- kernel 1: style s[b][c] = fc_coef * (y @ fc_w) + bias + 1
// grid (8 c-groups, 16 b), block 256: split-l reduction, 128 blocks
__global__ void style_k(const float* __restrict__ y, const float* __restrict__ fcw,
                        const float* __restrict__ bias, float* __restrict__ s) {
  const int cg = blockIdx.x, b = blockIdx.y;
  const int tid = threadIdx.x;
  const int cl = tid & 63, part = tid >> 6;
  const int c = cg * 64 + cl;
  __shared__ float ys[LAT];
  __shared__ float ps[4][64];
  ys[tid]       = y[b * LAT + tid];
  ys[tid + 256] = y[b * LAT + tid + 256];
  __syncthreads();
  float acc = 0.f;
  const float* fp = fcw + (part * 128) * C_IN + c;
#pragma unroll 8
  for (int l = 0; l < 128; ++l) acc += ys[part * 128 + l] * fp[l * C_IN];
  ps[part][cl] = acc;
  __syncthreads();
  if (part == 0) {
    float r = ps[0][cl] + ps[1][cl] + ps[2][cl] + ps[3][cl];
    s[b * C_IN + c] = r * FC_COEF + bias[c] + 1.0f;
  }
}

// ---------------- kernel 2: wb[tap][o][c] = bf16(w*RC)  (transposed), t[c][o] = sum_tap (w*RC)^2
__global__ void wtrans_k(const float* __restrict__ w, unsigned short* __restrict__ wb,
                         float* __restrict__ t) {
  // grid (C_OUT/64, C_IN/64), block 256
  const int o0 = blockIdx.x * 64, c0 = blockIdx.y * 64;
  __shared__ unsigned short tile[64][66];
  const int tid = threadIdx.x;
  float acc[16];
#pragma unroll
  for (int i = 0; i < 16; ++i) acc[i] = 0.f;
  for (int tap = 0; tap < 9; ++tap) {
    __syncthreads();
#pragma unroll
    for (int i = 0; i < 16; ++i) {
      int row = i * 4 + (tid >> 6);   // c offset
      int col = tid & 63;             // o offset
      float v = w[(tap * C_IN + c0 + row) * C_OUT + o0 + col] * RC;
      acc[i] += v * v;
      tile[row][col] = f2bf(v);
    }
    __syncthreads();
#pragma unroll
    for (int i = 0; i < 16; ++i) {
      int row = i * 4 + (tid >> 6);   // o offset
      int col = tid & 63;             // c offset
      wb[(tap * C_OUT + o0 + row) * C_IN + c0 + col] = tile[col][row];
    }
  }
#pragma unroll
  for (int i = 0; i < 16; ++i) {
    int row = i * 4 + (tid >> 6), col = tid & 63;
    t[(c0 + row) * C_OUT + o0 + col] = acc[i];
  }
}

// ---------------- kernel 3: d[b][o] = rsqrt(sum_c s^2 * t + eps)
// grid (8 o-groups, 16 b), block 256: split-c reduction, 128 blocks
__global__ void demod_k(const float* __restrict__ s, const float* __restrict__ t,
                        float* __restrict__ d) {
  const int og = blockIdx.x, b = blockIdx.y;
  const int tid = threadIdx.x;
  const int ol = tid & 63, part = tid >> 6;
  const int o = og * 64 + ol;
  __shared__ float ssq[C_IN];
  __shared__ float ps[4][64];
  float v0 = s[b * C_IN + tid];       ssq[tid] = v0 * v0;
  float v1 = s[b * C_IN + tid + 256]; ssq[tid + 256] = v1 * v1;
  __syncthreads();
  float acc = 0.f;
  const float* tp = t + (part * 128) * C_OUT + o;
#pragma unroll 8
  for (int c = 0; c < 128; ++c) acc += ssq[part * 128 + c] * tp[c * C_OUT];
  ps[part][ol] = acc;
  __syncthreads();
  if (part == 0)
    d[b * C_OUT + o] = rsqrtf(ps[0][ol] + ps[1][ol] + ps[2][ol] + ps[3][ol] + 1e-8f);
}

// ---------------- kernel 4: xg[b][h+1][w][c] = bf16(x[b][c][h][w] * s[b][c]) with zero guard rows
// grid (66 rows, 8 c-groups, 16 b), block 256
__global__ void modx_k(const float* __restrict__ x, const float* __restrict__ s,
                       unsigned short* __restrict__ xg) {
  const int rowx = blockIdx.x;          // 0..65 (row 0 and 65 are zero guards)
  const int cg = blockIdx.y, b = blockIdx.z;
  const int c0 = cg * 64;
  const int tid = threadIdx.x;
  unsigned short* orow = xg + (size_t)(b * 66 + rowx) * 64 * 512;
  if (rowx == 0 || rowx == 65) {
    const short8 z = {0, 0, 0, 0, 0, 0, 0, 0};
    int r = tid >> 2, q = tid & 3;
    *(short8*)(orow + r * 512 + c0 + q * 16) = z;
    *(short8*)(orow + r * 512 + c0 + q * 16 + 8) = z;
    return;
  }
  const int h = rowx - 1;
  __shared__ unsigned short tile[64][66];
#pragma unroll
  for (int i = 0; i < 16; ++i) {
    int row = i * 4 + (tid >> 6);   // c offset
    int col = tid & 63;             // w
    float v = x[((b * C_IN + c0 + row) * H_ + h) * W_ + col] * s[b * C_IN + c0 + row];
    tile[row][col] = f2bf(v);
  }
  __syncthreads();
#pragma unroll
  for (int i = 0; i < 16; ++i) {
    int row = i * 4 + (tid >> 6);   // w
    int col = tid & 63;             // c offset
    orow[row * 512 + c0 + col] = tile[col][row];
  }
}

// ---------------- kernel 5: conv, counted-vmcnt pipeline
// grid (16 pixel-blocks(4 rows), 4 cout-blocks, 16 b), block 512 (8 waves, each 64cout x 64pix)
__global__ __launch_bounds__(512, 4)   // 4 waves/EU = 2 blocks/CU (72KB LDS each)
void conv_k(const unsigned short* __restrict__ xg,
            const unsigned short* __restrict__ wb,
            const float* __restrict__ d,
            float* __restrict__ out) {
  // LDS: x 2 x 12288 shorts (6 halo rows x 64 x 32ch) + w 3 x 4096 shorts (128 x 32ch) = 72 KB
  __shared__ __align__(16) unsigned short lds[36864];
  const int tid = threadIdx.x;
  const int pb = blockIdx.x;
  const int ob = blockIdx.y;
  const int b  = blockIdx.z;
  const int h0 = pb * 4;
  const int p0 = pb * 256;
  const int o0 = ob * 128;

  const int lane = tid & 63;
  const int wv   = tid >> 6;
  const int wm   = wv >> 2;      // 0..1 cout group
  const int wn   = wv & 3;       // 0..3 pixel-row group
  const int kg   = lane >> 4;
  const int l16  = lane & 15;

  unsigned short* const xsb0 = lds;
  unsigned short* const xsb1 = lds + 12288;
  unsigned short* const wsl[3] = { lds + 24576, lds + 28672, lds + 32768 };

  int a_off[4];
#pragma unroll
  for (int mf = 0; mf < 4; ++mf) {
    int m = wm * 64 + mf * 16 + l16;
    a_off[mf] = (m * 4 + (kg ^ ((m >> 1) & 3))) * 8;
  }
  int pcc[4];
#pragma unroll
  for (int nf = 0; nf < 4; ++nf) pcc[nf] = nf * 16 + l16;

  const f32x4 fzero = {0.f, 0.f, 0.f, 0.f};
  const short8 szero = {0, 0, 0, 0, 0, 0, 0, 0};
  f32x4 acc[4][4];
#pragma unroll
  for (int i = 0; i < 4; ++i)
#pragma unroll
    for (int j = 0; j < 4; ++j) acc[i][j] = fzero;

  const unsigned short* xb_b = xg + (size_t)b * 66 * 64 * 512;

  // 3 loads/thread, image rows h0-1..h0+4 are guard-padded rows h0..h0+5
  auto stage_x = [&](unsigned short* dst, int c0) {
#pragma unroll
    for (int j = 0; j < 3; ++j) {
      int lin = j * 512 + tid;
      int r = lin >> 8, col = (lin >> 2) & 63, sx = lin & 3;
      int g = sx ^ ((col >> 1) & 3);
      gload_lds16(xb_b + ((h0 + r) * 64 + col) * 512 + c0 + g * 8, dst + lin * 8);
    }
  };
  // 1 load/thread
  auto stage_w = [&](unsigned short* dst, int tap, int c0) {
    int m = tid >> 2, sx = tid & 3;
    int g = sx ^ ((m >> 1) & 3);
    gload_lds16(wb + (tap * C_OUT + o0 + m) * C_IN + c0 + g * 8, dst + tid * 8);
  };

  // prologue: x(chunk0)[3], w(tap0)[1], w(tap1)[1] -> 5 outstanding
  stage_x(xsb0, 0);
  stage_w(wsl[0], 0, 0);
  stage_w(wsl[1], 1, 0);

  for (int chunk = 0; chunk < 16; ++chunk) {
    const int c0  = chunk * 32;
    const int c0n = ((chunk + 1) & 15) * 32;
    unsigned short* xs = (chunk & 1) ? xsb1 : xsb0;
#pragma unroll
    for (int t = 0; t < 9; ++t) {
      // stage 2 taps ahead; at t==6 also stage next chunk's x AFTER w8 so that
      // the x loads are only force-drained at next chunk's t==0 (when needed).
      if (t < 7) stage_w(wsl[(t + 2) % 3], t + 2, c0);
      else       stage_w(wsl[(t + 2) % 3], t - 7, c0n);
      if (t == 6) stage_x((chunk & 1) ? xsb0 : xsb1, c0n);
      // steady state: t<6 -> [w_t, w_t+1, w_t+2] or chunk-start [x3,w0,w1,w2]: drain to 2
      //               t>=6 -> 6 outstanding incl. x': drain to 5 (just-oldest w)
      asm volatile("s_waitcnt vmcnt(%0)" :: "i"(t < 6 ? 2 : 5) : "memory");
      __builtin_amdgcn_s_barrier();
      __builtin_amdgcn_sched_barrier(0);

      const int kh = t / 3, kw = t % 3;
      const unsigned short* wt = wsl[t % 3];
      short8 af[4];
#pragma unroll
      for (int mf = 0; mf < 4; ++mf)
        af[mf] = *(const short8*)(wt + a_off[mf]);
      __builtin_amdgcn_s_setprio(1);
#pragma unroll
      for (int nf = 0; nf < 4; ++nf) {
        int ct = pcc[nf] + kw - 1;
        bool vd = (unsigned)ct < 64u;
        int ctc = ct & 63;
        int slot = ((wn + kh) * 64 + ctc) * 4 + (kg ^ ((ctc >> 1) & 3));
        short8 tv = *(const short8*)(xs + slot * 8);
        short8 bf = vd ? tv : szero;
#pragma unroll
        for (int mf = 0; mf < 4; ++mf)
          acc[mf][nf] = __builtin_amdgcn_mfma_f32_16x16x32_bf16(af[mf], bf, acc[mf][nf], 0, 0, 0);
      }
      __builtin_amdgcn_s_setprio(0);
      __builtin_amdgcn_sched_barrier(0);
      __builtin_amdgcn_s_barrier();
    }
  }

  // epilogue: out[b][o][p] = acc * d[b][o]
  const float* db = d + b * C_OUT;
  float* obase = out + (size_t)b * C_OUT * 4096;
#pragma unroll
  for (int mf = 0; mf < 4; ++mf) {
#pragma unroll
    for (int rg = 0; rg < 4; ++rg) {
      int o = o0 + wm * 64 + mf * 16 + kg * 4 + rg;
      float dv = db[o];
      float* orow = obase + (size_t)o * 4096 + p0 + wn * 64;
#pragma unroll
      for (int nf = 0; nf < 4; ++nf)
        orow[nf * 16 + l16] = acc[mf][nf][rg] * dv;
    }
  }
}

extern "C" void kernel_launch(void* const* d_in, const int* in_sizes, int n_in,
                              void* d_out, int out_size, void* d_ws, size_t ws_size,
                              hipStream_t stream) {
  const float* x    = (const float*)d_in[0];
  const float* y    = (const float*)d_in[1];
  const float* w    = (const float*)d_in[2];
  const float* fcw  = (const float*)d_in[3];
  const float* bias = (const float*)d_in[4];
  float* out = (float*)d_out;

  char* ws = (char*)d_ws;
  float* s_buf          = (float*)(ws);                    //  32 KB  s[16][512]
  float* d_buf          = (float*)(ws + 32768);            //  32 KB  d[16][512]
  float* t_buf          = (float*)(ws + 65536);            //   1 MB  t[512][512]
  unsigned short* wbuf  = (unsigned short*)(ws + 1114112); // 4.5 MB  wb[9][512][512] bf16
  unsigned short* xgbuf = (unsigned short*)(ws + 5832704); //  66 MB  xg[16][66][64][512] bf16

  style_k<<<dim3(8, 16), dim3(256), 0, stream>>>(y, fcw, bias, s_buf);
  wtrans_k<<<dim3(8, 8), dim3(256), 0, stream>>>(w, wbuf, t_buf);
  demod_k<<<dim3(8, 16), dim3(256), 0, stream>>>(s_buf, t_buf, d_buf);
  modx_k<<<dim3(66, 8, 16), dim3(256), 0, stream>>>(x, s_buf, xgbuf);
  conv_k<<<dim3(16, 4, 16), dim3(512), 0, stream>>>(xgbuf, wbuf, d_buf, out);
}